// Round 4
// baseline (584.540 us; speedup 1.0000x reference)
//
#include <hip/hip_runtime.h>

// EllipticGNN: 2-layer GCN + linear head, f32. CSR-gather aggregation
// (wave-per-node, float2 lanes, unroll-8 MLP) + LDS-tiled GEMM.

constexpr int NN   = 100000;
constexpr int NE   = 1600000;
constexpr int FIN  = 165;
constexpr int HID  = 128;

__global__ __launch_bounds__(256) void k_zero_counts(int* __restrict__ c) {
    int i = blockIdx.x * 256 + threadIdx.x;
    if (i < NN) c[i] = 0;
}

__global__ __launch_bounds__(256) void k_hist(const int* __restrict__ dst,
                                              int* __restrict__ c) {
    int i = blockIdx.x * 256 + threadIdx.x;
    if (i < NE) atomicAdd(&c[dst[i]], 1);
}

__global__ __launch_bounds__(256) void k_dinv(const int* __restrict__ c,
                                              float* __restrict__ dinv) {
    int i = blockIdx.x * 256 + threadIdx.x;
    if (i < NN) dinv[i] = rsqrtf((float)c[i] + 1.0f);   // +1 self-loop
}

// block-level exclusive scan of counts -> rowptr (partial), block sums -> bsum
__global__ __launch_bounds__(256) void k_scanA(const int* __restrict__ c,
                                               int* __restrict__ rowptr,
                                               int* __restrict__ bsum) {
    __shared__ int s[256];
    int t = threadIdx.x;
    int i = blockIdx.x * 256 + t;
    int v = (i < NN) ? c[i] : 0;
    s[t] = v; __syncthreads();
    for (int off = 1; off < 256; off <<= 1) {
        int add = (t >= off) ? s[t - off] : 0;
        __syncthreads();
        s[t] += add;
        __syncthreads();
    }
    if (i < NN) rowptr[i] = s[t] - v;          // exclusive within block
    if (t == 255) bsum[blockIdx.x] = s[255];
}

// exclusive scan of block sums in place (nb <= 512)
__global__ __launch_bounds__(512) void k_scanB(int* __restrict__ bsum, int nb) {
    __shared__ int s[512];
    int t = threadIdx.x;
    int v = (t < nb) ? bsum[t] : 0;
    s[t] = v; __syncthreads();
    for (int off = 1; off < 512; off <<= 1) {
        int add = (t >= off) ? s[t - off] : 0;
        __syncthreads();
        s[t] += add;
        __syncthreads();
    }
    if (t < nb) bsum[t] = s[t] - v;
}

// add block offsets; re-zero counts (reused as fill cursor); rowptr[NN] = NE
__global__ __launch_bounds__(256) void k_scanC(int* __restrict__ rowptr,
                                               const int* __restrict__ bsum,
                                               int* __restrict__ c) {
    int i = blockIdx.x * 256 + threadIdx.x;
    if (i < NN) { rowptr[i] += bsum[blockIdx.x]; c[i] = 0; }
    if (i == 0) rowptr[NN] = NE;
}

__global__ __launch_bounds__(256) void k_fill(const int* __restrict__ src,
                                              const int* __restrict__ dst,
                                              const float* __restrict__ dinv,
                                              const int* __restrict__ rowptr,
                                              int* __restrict__ cur,
                                              int* __restrict__ col,
                                              float* __restrict__ wv) {
    int e = blockIdx.x * 256 + threadIdx.x;
    if (e >= NE) return;
    int s = src[e], d = dst[e];
    int pos = rowptr[d] + atomicAdd(&cur[d], 1);
    col[pos] = s;
    wv[pos]  = dinv[s];
}

// Tiled GEMM: Y[64 x 128 tile] = X[64 x K] @ W[K x 128].
template<int K, int KP, bool VEC4>
__global__ __launch_bounds__(256) void k_gemm_t(const float* __restrict__ X,
                                                const float* __restrict__ W,
                                                float* __restrict__ Y) {
    __shared__ float Xs[64 * KP];
    const int tid = threadIdx.x;
    const long base = (long)blockIdx.x * 64;
    const int rows = (NN - base < 64) ? (int)(NN - base) : 64;

    if (VEC4) {
        const float4* Xg = (const float4*)(X + base * K);
        const int tot4 = rows * (K / 4);
        for (int i = tid; i < tot4; i += 256) {
            int r = i / (K / 4), c4 = i % (K / 4);
            *(float4*)&Xs[r * KP + c4 * 4] = Xg[i];
        }
    } else {
        const int tot = rows * K;
        const float* Xg = X + base * K;
        for (int i = tid; i < tot; i += 256) {
            int r = i / K, c = i % K;
            Xs[r * KP + c] = Xg[i];
        }
    }
    __syncthreads();

    const int cg = tid & 31;
    const int rg = tid >> 5;
    const float* Wp = W + 4 * cg;
    const float* Xrow = &Xs[rg * 8 * KP];

    float acc[8][4];
#pragma unroll
    for (int r = 0; r < 8; ++r)
#pragma unroll
        for (int c = 0; c < 4; ++c) acc[r][c] = 0.0f;

    int k = 0;
    for (; k + 4 <= K; k += 4) {
        float4 w0 = *(const float4*)(Wp + (k + 0) * HID);
        float4 w1 = *(const float4*)(Wp + (k + 1) * HID);
        float4 w2 = *(const float4*)(Wp + (k + 2) * HID);
        float4 w3 = *(const float4*)(Wp + (k + 3) * HID);
#pragma unroll
        for (int r = 0; r < 8; ++r) {
            float4 xv = *(const float4*)&Xrow[r * KP + k];
            acc[r][0] += xv.x * w0.x + xv.y * w1.x + xv.z * w2.x + xv.w * w3.x;
            acc[r][1] += xv.x * w0.y + xv.y * w1.y + xv.z * w2.y + xv.w * w3.y;
            acc[r][2] += xv.x * w0.z + xv.y * w1.z + xv.z * w2.z + xv.w * w3.z;
            acc[r][3] += xv.x * w0.w + xv.y * w1.w + xv.z * w2.w + xv.w * w3.w;
        }
    }
    for (; k < K; ++k) {                       // tail (K=165)
        float4 wt = *(const float4*)(Wp + k * HID);
#pragma unroll
        for (int r = 0; r < 8; ++r) {
            float xs = Xrow[r * KP + k];
            acc[r][0] += xs * wt.x;
            acc[r][1] += xs * wt.y;
            acc[r][2] += xs * wt.z;
            acc[r][3] += xs * wt.w;
        }
    }

#pragma unroll
    for (int r = 0; r < 8; ++r) {
        long row = base + rg * 8 + r;
        if (row < NN) {
            float4 o = make_float4(acc[r][0], acc[r][1], acc[r][2], acc[r][3]);
            *(float4*)&Y[row * HID + 4 * cg] = o;
        }
    }
}

// Wave-per-node CSR gather: out[i][:] = relu(dinv[i]*(H[i]*dinv[i] +
// sum_k wv[k]*H[col[k]]) + b). Lane j owns cols {2j, 2j+1} (float2);
// edge loop unrolled x8 -> 8 independent dwordx2 gathers in flight.
template<bool RELU>
__global__ __launch_bounds__(64) void k_agg(const float* __restrict__ Hm,
                                            const int* __restrict__ rowptr,
                                            const int* __restrict__ col,
                                            const float* __restrict__ wv,
                                            const float* __restrict__ dinv,
                                            const float* __restrict__ bias,
                                            float* __restrict__ out) {
    const int i = blockIdx.x;
    const int j = threadIdx.x;               // 0..63
    const float di = dinv[i];
    const float2* H2 = (const float2*)Hm;    // row stride 64 float2
    int k = rowptr[i];
    const int end = rowptr[i + 1];

    float2 self = H2[(long)i * 64 + j];
    float a0 = self.x * di;
    float a1 = self.y * di;

    for (; k + 8 <= end; k += 8) {
        int   s[8];
        float w[8];
#pragma unroll
        for (int u = 0; u < 8; ++u) { s[u] = col[k + u]; w[u] = wv[k + u]; }
        float2 h[8];
#pragma unroll
        for (int u = 0; u < 8; ++u) h[u] = H2[(long)s[u] * 64 + j];
#pragma unroll
        for (int u = 0; u < 8; ++u) { a0 += w[u] * h[u].x; a1 += w[u] * h[u].y; }
    }
    for (; k + 2 <= end; k += 2) {
        int   s0 = col[k], s1 = col[k + 1];
        float w0 = wv[k],  w1 = wv[k + 1];
        float2 h0 = H2[(long)s0 * 64 + j];
        float2 h1 = H2[(long)s1 * 64 + j];
        a0 += w0 * h0.x + w1 * h1.x;
        a1 += w0 * h0.y + w1 * h1.y;
    }
    if (k < end) {
        float w0 = wv[k];
        float2 h0 = H2[(long)col[k] * 64 + j];
        a0 += w0 * h0.x;
        a1 += w0 * h0.y;
    }

    float2 bb = ((const float2*)bias)[j];
    float r0 = di * a0 + bb.x;
    float r1 = di * a1 + bb.y;
    if (RELU) { r0 = fmaxf(r0, 0.f); r1 = fmaxf(r1, 0.f); }
    ((float2*)out)[(long)i * 64 + j] = make_float2(r0, r1);
}

__global__ __launch_bounds__(256) void k_head(const float* __restrict__ h,
                                              const float* __restrict__ W3,
                                              const float* __restrict__ b3,
                                              float* __restrict__ out) {
    __shared__ float w[HID * 2];
    int t = threadIdx.x;
    w[t] = W3[t];               // 256 = HID*2 exactly
    __syncthreads();
    int i = blockIdx.x * 256 + t;
    if (i >= NN) return;
    const float4* row = (const float4*)(h + (long)i * HID);
    float a0 = 0.f, a1 = 0.f;
#pragma unroll
    for (int k4 = 0; k4 < HID / 4; ++k4) {
        float4 v = row[k4];
        a0 += v.x * w[(k4 * 4 + 0) * 2 + 0] + v.y * w[(k4 * 4 + 1) * 2 + 0]
            + v.z * w[(k4 * 4 + 2) * 2 + 0] + v.w * w[(k4 * 4 + 3) * 2 + 0];
        a1 += v.x * w[(k4 * 4 + 0) * 2 + 1] + v.y * w[(k4 * 4 + 1) * 2 + 1]
            + v.z * w[(k4 * 4 + 2) * 2 + 1] + v.w * w[(k4 * 4 + 3) * 2 + 1];
    }
    out[(long)i * 2 + 0] = a0 + b3[0];
    out[(long)i * 2 + 1] = a1 + b3[1];
}

extern "C" void kernel_launch(void* const* d_in, const int* in_sizes, int n_in,
                              void* d_out, int out_size, void* d_ws, size_t ws_size,
                              hipStream_t stream) {
    const float* x   = (const float*)d_in[0];
    const int*   ei  = (const int*)d_in[1];
    const float* W1  = (const float*)d_in[2];
    const float* b1  = (const float*)d_in[3];
    const float* W2  = (const float*)d_in[4];
    const float* b2  = (const float*)d_in[5];
    const float* W3  = (const float*)d_in[6];
    const float* b3  = (const float*)d_in[7];
    float* out = (float*)d_out;

    const int* srcA = ei;           // edge_index[0]
    const int* dstA = ei + NE;      // edge_index[1]

    // workspace layout (256B-aligned slabs)
    char* p = (char*)d_ws;
    auto alloc = [&](size_t bytes) {
        char* r = p;
        p += (bytes + 255) & ~(size_t)255;
        return r;
    };
    float* dinv   = (float*)alloc(NN * 4);
    int*   counts = (int*)  alloc(NN * 4);          // later reused as cursor
    int*   rowptr = (int*)  alloc((NN + 1) * 4);
    int*   bsum   = (int*)  alloc(512 * 4);
    int*   col    = (int*)  alloc((size_t)NE * 4);
    float* wv     = (float*)alloc((size_t)NE * 4);
    float* buf1   = (float*)alloc((size_t)NN * HID * 4);
    float* buf2   = (float*)alloc((size_t)NN * HID * 4);

    const int nb_n = (NN + 255) / 256;   // 391
    const int nb_e = (NE + 255) / 256;   // 6250
    const int nb_g = (NN + 63) / 64;     // 1563

    // ---- CSR build ----
    k_zero_counts<<<nb_n, 256, 0, stream>>>(counts);
    k_hist<<<nb_e, 256, 0, stream>>>(dstA, counts);
    k_dinv<<<nb_n, 256, 0, stream>>>(counts, dinv);
    k_scanA<<<nb_n, 256, 0, stream>>>(counts, rowptr, bsum);
    k_scanB<<<1, 512, 0, stream>>>(bsum, nb_n);
    k_scanC<<<nb_n, 256, 0, stream>>>(rowptr, bsum, counts);
    k_fill<<<nb_e, 256, 0, stream>>>(srcA, dstA, dinv, rowptr, counts, col, wv);

    // ---- layer 1 ----  (K=165, LDS row stride 168 keeps 16B alignment)
    k_gemm_t<FIN, 168, false><<<nb_g, 256, 0, stream>>>(x, W1, buf1);
    k_agg<true><<<NN, 64, 0, stream>>>(buf1, rowptr, col, wv, dinv, b1, buf2);

    // ---- layer 2 ----  (K=128, stride 132 = 16B-aligned, float4 staging)
    k_gemm_t<HID, 132, true><<<nb_g, 256, 0, stream>>>(buf2, W2, buf1);
    k_agg<true><<<NN, 64, 0, stream>>>(buf1, rowptr, col, wv, dinv, b2, buf2);

    // ---- head ----
    k_head<<<nb_n, 256, 0, stream>>>(buf2, W3, b3, out);
}

// Round 5
// 530.199 us; speedup vs baseline: 1.1025x; 1.1025x over previous
//
#include <hip/hip_runtime.h>

// EllipticGNN: 2-layer GCN + linear head, f32.
// CSR gather agg; gemm2 fused into agg1 (GEMV under memory stalls);
// head fused into agg2.

constexpr int NN   = 100000;
constexpr int NE   = 1600000;
constexpr int FIN  = 165;
constexpr int HID  = 128;

__global__ __launch_bounds__(256) void k_zero_counts(int* __restrict__ c) {
    int i = blockIdx.x * 256 + threadIdx.x;
    if (i < NN) c[i] = 0;
}

__global__ __launch_bounds__(256) void k_hist(const int* __restrict__ dst,
                                              int* __restrict__ c) {
    int i = blockIdx.x * 256 + threadIdx.x;
    if (i < NE) atomicAdd(&c[dst[i]], 1);
}

__global__ __launch_bounds__(256) void k_dinv(const int* __restrict__ c,
                                              float* __restrict__ dinv) {
    int i = blockIdx.x * 256 + threadIdx.x;
    if (i < NN) dinv[i] = rsqrtf((float)c[i] + 1.0f);   // +1 self-loop
}

__global__ __launch_bounds__(256) void k_scanA(const int* __restrict__ c,
                                               int* __restrict__ rowptr,
                                               int* __restrict__ bsum) {
    __shared__ int s[256];
    int t = threadIdx.x;
    int i = blockIdx.x * 256 + t;
    int v = (i < NN) ? c[i] : 0;
    s[t] = v; __syncthreads();
    for (int off = 1; off < 256; off <<= 1) {
        int add = (t >= off) ? s[t - off] : 0;
        __syncthreads();
        s[t] += add;
        __syncthreads();
    }
    if (i < NN) rowptr[i] = s[t] - v;
    if (t == 255) bsum[blockIdx.x] = s[255];
}

__global__ __launch_bounds__(512) void k_scanB(int* __restrict__ bsum, int nb) {
    __shared__ int s[512];
    int t = threadIdx.x;
    int v = (t < nb) ? bsum[t] : 0;
    s[t] = v; __syncthreads();
    for (int off = 1; off < 512; off <<= 1) {
        int add = (t >= off) ? s[t - off] : 0;
        __syncthreads();
        s[t] += add;
        __syncthreads();
    }
    if (t < nb) bsum[t] = s[t] - v;
}

__global__ __launch_bounds__(256) void k_scanC(int* __restrict__ rowptr,
                                               const int* __restrict__ bsum,
                                               int* __restrict__ c) {
    int i = blockIdx.x * 256 + threadIdx.x;
    if (i < NN) { rowptr[i] += bsum[blockIdx.x]; c[i] = 0; }
    if (i == 0) rowptr[NN] = NE;
}

__global__ __launch_bounds__(256) void k_fill(const int* __restrict__ src,
                                              const int* __restrict__ dst,
                                              const float* __restrict__ dinv,
                                              const int* __restrict__ rowptr,
                                              int* __restrict__ cur,
                                              int* __restrict__ col,
                                              float* __restrict__ wv) {
    int e = blockIdx.x * 256 + threadIdx.x;
    if (e >= NE) return;
    int s = src[e], d = dst[e];
    int pos = rowptr[d] + atomicAdd(&cur[d], 1);
    col[pos] = s;
    wv[pos]  = dinv[s];
}

// Tiled GEMM: Y[64 x 128 tile] = X[64 x K] @ W[K x 128].
template<int K, int KP, bool VEC4>
__global__ __launch_bounds__(256) void k_gemm_t(const float* __restrict__ X,
                                                const float* __restrict__ W,
                                                float* __restrict__ Y) {
    __shared__ float Xs[64 * KP];
    const int tid = threadIdx.x;
    const long base = (long)blockIdx.x * 64;
    const int rows = (NN - base < 64) ? (int)(NN - base) : 64;

    if (VEC4) {
        const float4* Xg = (const float4*)(X + base * K);
        const int tot4 = rows * (K / 4);
        for (int i = tid; i < tot4; i += 256) {
            int r = i / (K / 4), c4 = i % (K / 4);
            *(float4*)&Xs[r * KP + c4 * 4] = Xg[i];
        }
    } else {
        const int tot = rows * K;
        const float* Xg = X + base * K;
        for (int i = tid; i < tot; i += 256) {
            int r = i / K, c = i % K;
            Xs[r * KP + c] = Xg[i];
        }
    }
    __syncthreads();

    const int cg = tid & 31;
    const int rg = tid >> 5;
    const float* Wp = W + 4 * cg;
    const float* Xrow = &Xs[rg * 8 * KP];

    float acc[8][4];
#pragma unroll
    for (int r = 0; r < 8; ++r)
#pragma unroll
        for (int c = 0; c < 4; ++c) acc[r][c] = 0.0f;

    int k = 0;
    for (; k + 4 <= K; k += 4) {
        float4 w0 = *(const float4*)(Wp + (k + 0) * HID);
        float4 w1 = *(const float4*)(Wp + (k + 1) * HID);
        float4 w2 = *(const float4*)(Wp + (k + 2) * HID);
        float4 w3 = *(const float4*)(Wp + (k + 3) * HID);
#pragma unroll
        for (int r = 0; r < 8; ++r) {
            float4 xv = *(const float4*)&Xrow[r * KP + k];
            acc[r][0] += xv.x * w0.x + xv.y * w1.x + xv.z * w2.x + xv.w * w3.x;
            acc[r][1] += xv.x * w0.y + xv.y * w1.y + xv.z * w2.y + xv.w * w3.y;
            acc[r][2] += xv.x * w0.z + xv.y * w1.z + xv.z * w2.z + xv.w * w3.z;
            acc[r][3] += xv.x * w0.w + xv.y * w1.w + xv.z * w2.w + xv.w * w3.w;
        }
    }
    for (; k < K; ++k) {
        float4 wt = *(const float4*)(Wp + k * HID);
#pragma unroll
        for (int r = 0; r < 8; ++r) {
            float xs = Xrow[r * KP + k];
            acc[r][0] += xs * wt.x;
            acc[r][1] += xs * wt.y;
            acc[r][2] += xs * wt.z;
            acc[r][3] += xs * wt.w;
        }
    }

#pragma unroll
    for (int r = 0; r < 8; ++r) {
        long row = base + rg * 8 + r;
        if (row < NN) {
            float4 o = make_float4(acc[r][0], acc[r][1], acc[r][2], acc[r][3]);
            *(float4*)&Y[row * HID + 4 * cg] = o;
        }
    }
}

// Gather one node's aggregated row into (a0,a1) for lane j (cols 2j,2j+1).
__device__ __forceinline__ void gather_row(const float2* __restrict__ H2,
                                           const int* __restrict__ rowptr,
                                           const int* __restrict__ col,
                                           const float* __restrict__ wv,
                                           int i, int j, float di,
                                           float& a0, float& a1) {
    int k = rowptr[i];
    const int end = rowptr[i + 1];
    float2 self = H2[(long)i * 64 + j];
    a0 = self.x * di;
    a1 = self.y * di;
    for (; k + 8 <= end; k += 8) {
        int   s[8];
        float w[8];
#pragma unroll
        for (int u = 0; u < 8; ++u) { s[u] = col[k + u]; w[u] = wv[k + u]; }
        float2 h[8];
#pragma unroll
        for (int u = 0; u < 8; ++u) h[u] = H2[(long)s[u] * 64 + j];
#pragma unroll
        for (int u = 0; u < 8; ++u) { a0 += w[u] * h[u].x; a1 += w[u] * h[u].y; }
    }
    for (; k + 2 <= end; k += 2) {
        int   s0 = col[k], s1 = col[k + 1];
        float w0 = wv[k],  w1 = wv[k + 1];
        float2 h0 = H2[(long)s0 * 64 + j];
        float2 h1 = H2[(long)s1 * 64 + j];
        a0 += w0 * h0.x + w1 * h1.x;
        a1 += w0 * h0.y + w1 * h1.y;
    }
    if (k < end) {
        float w0 = wv[k];
        float2 h0 = H2[(long)col[k] * 64 + j];
        a0 += w0 * h0.x;
        a1 += w0 * h0.y;
    }
}

// aggA: one wave per 8 nodes. Per node: gather + b1 + relu -> row in LDS.
// Then mini-GEMM (8 x 128) x W2 (128 x 128): q[node] = h2[node] @ W2.
__global__ __launch_bounds__(64) void k_aggA(const float* __restrict__ Hm,
                                             const int* __restrict__ rowptr,
                                             const int* __restrict__ col,
                                             const float* __restrict__ wv,
                                             const float* __restrict__ dinv,
                                             const float* __restrict__ b1,
                                             const float* __restrict__ W2,
                                             float* __restrict__ q) {
    __shared__ float vlds[8 * 128];
    const int j = threadIdx.x;                    // 0..63
    const int base = blockIdx.x * 8;
    const float2* H2 = (const float2*)Hm;
    const float2 bb = ((const float2*)b1)[j];

#pragma unroll
    for (int n = 0; n < 8; ++n) {
        const int i = base + n;
        const float di = dinv[i];
        float a0, a1;
        gather_row(H2, rowptr, col, wv, i, j, di, a0, a1);
        float r0 = fmaxf(di * a0 + bb.x, 0.0f);
        float r1 = fmaxf(di * a1 + bb.y, 0.0f);
        *(float2*)&vlds[n * 128 + 2 * j] = make_float2(r0, r1);
    }
    __syncthreads();

    // q[n][2j,2j+1] = sum_k vlds[n][k] * W2[k][2j,2j+1]
    float2 acc[8];
#pragma unroll
    for (int n = 0; n < 8; ++n) acc[n] = make_float2(0.f, 0.f);
    const float* Wp = W2 + 2 * j;
    for (int k4 = 0; k4 < 32; ++k4) {
        float2 w0 = *(const float2*)(Wp + (k4 * 4 + 0) * HID);
        float2 w1 = *(const float2*)(Wp + (k4 * 4 + 1) * HID);
        float2 w2 = *(const float2*)(Wp + (k4 * 4 + 2) * HID);
        float2 w3 = *(const float2*)(Wp + (k4 * 4 + 3) * HID);
#pragma unroll
        for (int n = 0; n < 8; ++n) {
            float4 v = *(const float4*)&vlds[n * 128 + k4 * 4];  // uniform -> broadcast
            acc[n].x += v.x * w0.x + v.y * w1.x + v.z * w2.x + v.w * w3.x;
            acc[n].y += v.x * w0.y + v.y * w1.y + v.z * w2.y + v.w * w3.y;
        }
    }
#pragma unroll
    for (int n = 0; n < 8; ++n)
        ((float2*)q)[(long)(base + n) * 64 + j] = acc[n];
}

// aggB: one wave per 4 nodes. Per node: gather q + b2 + relu, then head
// (x W3 + b3) via wave reduction -> out[i][0..1].
__global__ __launch_bounds__(64) void k_aggB(const float* __restrict__ Qm,
                                             const int* __restrict__ rowptr,
                                             const int* __restrict__ col,
                                             const float* __restrict__ wv,
                                             const float* __restrict__ dinv,
                                             const float* __restrict__ b2,
                                             const float* __restrict__ W3,
                                             const float* __restrict__ b3,
                                             float* __restrict__ out) {
    const int j = threadIdx.x;
    const int base = blockIdx.x * 4;
    const float2* Q2 = (const float2*)Qm;
    const float2 bb = ((const float2*)b2)[j];
    // W3 rows 2j, 2j+1, both cols: [W3[2j][0], W3[2j][1], W3[2j+1][0], W3[2j+1][1]]
    const float4 w3v = *(const float4*)&W3[2 * j * 2];
    const float b30 = b3[0], b31 = b3[1];

#pragma unroll
    for (int n = 0; n < 4; ++n) {
        const int i = base + n;
        const float di = dinv[i];
        float a0, a1;
        gather_row(Q2, rowptr, col, wv, i, j, di, a0, a1);
        float r0 = fmaxf(di * a0 + bb.x, 0.0f);
        float r1 = fmaxf(di * a1 + bb.y, 0.0f);
        float p0 = r0 * w3v.x + r1 * w3v.z;
        float p1 = r0 * w3v.y + r1 * w3v.w;
#pragma unroll
        for (int m = 1; m < 64; m <<= 1) {
            p0 += __shfl_xor(p0, m);
            p1 += __shfl_xor(p1, m);
        }
        if (j == 0)
            ((float2*)out)[i] = make_float2(p0 + b30, p1 + b31);
    }
}

extern "C" void kernel_launch(void* const* d_in, const int* in_sizes, int n_in,
                              void* d_out, int out_size, void* d_ws, size_t ws_size,
                              hipStream_t stream) {
    const float* x   = (const float*)d_in[0];
    const int*   ei  = (const int*)d_in[1];
    const float* W1  = (const float*)d_in[2];
    const float* b1  = (const float*)d_in[3];
    const float* W2  = (const float*)d_in[4];
    const float* b2  = (const float*)d_in[5];
    const float* W3  = (const float*)d_in[6];
    const float* b3  = (const float*)d_in[7];
    float* out = (float*)d_out;

    const int* srcA = ei;
    const int* dstA = ei + NE;

    char* p = (char*)d_ws;
    auto alloc = [&](size_t bytes) {
        char* r = p;
        p += (bytes + 255) & ~(size_t)255;
        return r;
    };
    float* dinv   = (float*)alloc(NN * 4);
    int*   counts = (int*)  alloc(NN * 4);
    int*   rowptr = (int*)  alloc((NN + 1) * 4);
    int*   bsum   = (int*)  alloc(512 * 4);
    int*   col    = (int*)  alloc((size_t)NE * 4);
    float* wv     = (float*)alloc((size_t)NE * 4);
    float* buf1   = (float*)alloc((size_t)NN * HID * 4);   // h1 = X@W1
    float* buf2   = (float*)alloc((size_t)NN * HID * 4);   // q  = relu(agg1)@W2

    const int nb_n = (NN + 255) / 256;
    const int nb_e = (NE + 255) / 256;
    const int nb_g = (NN + 63) / 64;

    // ---- CSR build ----
    k_zero_counts<<<nb_n, 256, 0, stream>>>(counts);
    k_hist<<<nb_e, 256, 0, stream>>>(dstA, counts);
    k_dinv<<<nb_n, 256, 0, stream>>>(counts, dinv);
    k_scanA<<<nb_n, 256, 0, stream>>>(counts, rowptr, bsum);
    k_scanB<<<1, 512, 0, stream>>>(bsum, nb_n);
    k_scanC<<<nb_n, 256, 0, stream>>>(rowptr, bsum, counts);
    k_fill<<<nb_e, 256, 0, stream>>>(srcA, dstA, dinv, rowptr, counts, col, wv);

    // ---- layer 1 GEMM ----
    k_gemm_t<FIN, 168, false><<<nb_g, 256, 0, stream>>>(x, W1, buf1);

    // ---- agg1 + b1 + relu + GEMV W2 ----  (NN = 8 * 12500)
    k_aggA<<<NN / 8, 64, 0, stream>>>(buf1, rowptr, col, wv, dinv, b1, W2, buf2);

    // ---- agg2 + b2 + relu + head ----     (NN = 4 * 25000)
    k_aggB<<<NN / 4, 64, 0, stream>>>(buf2, rowptr, col, wv, dinv, b2, W3, b3, out);
}